// Round 1
// baseline (811.209 us; speedup 1.0000x reference)
//
#include <hip/hip_runtime.h>
#include <hip/hip_bf16.h>
#include <stdint.h>

#define D_MODEL 1024
#define SEQ     2048
#define NB      4
#define NH      16
#define DK      64

typedef __bf16 bf16x8 __attribute__((ext_vector_type(8)));
typedef float  f32x4  __attribute__((ext_vector_type(4)));
typedef unsigned short u16;

// fp32 -> bf16 round-to-nearest-even
__device__ __forceinline__ u16 f2bf(float f) {
    uint32_t u = __float_as_uint(f);
    u += 0x7FFFu + ((u >> 16) & 1u);
    return (u16)(u >> 16);
}

__global__ __launch_bounds__(256) void cvt_kernel(const float* __restrict__ src,
                                                  u16* __restrict__ dst, int n4) {
    int i = blockIdx.x * blockDim.x + threadIdx.x;
    if (i >= n4) return;
    float4 v = reinterpret_cast<const float4*>(src)[i];
    ushort4 o;
    o.x = f2bf(v.x); o.y = f2bf(v.y); o.z = f2bf(v.z); o.w = f2bf(v.w);
    reinterpret_cast<ushort4*>(dst)[i] = o;
}

// 64x64 output tile per wave. A: [M,K] K-major bf16 (pointer pre-offset to wave's
// 64 rows), B: [N,K] K-major bf16 (pre-offset). Verified layouts (learn_hip m89/m91):
//   A frag: A[m=lane&15][k=quad*8+j]   B frag: B[k=quad*8+j][n=lane&15]
//   C/D:    col(n)=lane&15, row(m)=quad*4+reg
__device__ __forceinline__ void gemm_tile_64x64(const u16* __restrict__ A,
                                                const u16* __restrict__ B,
                                                int K, f32x4 acc[4][4],
                                                int l15, int quad) {
    const u16* a0 = A + l15 * K + quad * 8;
    const u16* b0 = B + l15 * K + quad * 8;
#pragma unroll 2
    for (int k0 = 0; k0 < K; k0 += 32) {
        bf16x8 af[4], bfr[4];
#pragma unroll
        for (int s = 0; s < 4; ++s) {
            af[s]  = *reinterpret_cast<const bf16x8*>(a0 + s * 16 * K + k0);
            bfr[s] = *reinterpret_cast<const bf16x8*>(b0 + s * 16 * K + k0);
        }
#pragma unroll
        for (int ms = 0; ms < 4; ++ms)
#pragma unroll
            for (int ns = 0; ns < 4; ++ns)
                acc[ms][ns] = __builtin_amdgcn_mfma_f32_16x16x32_bf16(
                    af[ms], bfr[ns], acc[ms][ns], 0, 0, 0);
    }
}

// Fused QKV projection. z=0: Q (scaled by 0.125*log2e) -> [B,H,S,64]
//                       z=1: K -> [B,H,S,64]    z=2: V -> [B,H,64,S] (transposed)
__global__ __launch_bounds__(256) void qkv_gemm(
    const u16* __restrict__ xb,
    const u16* __restrict__ Wq, const u16* __restrict__ Wk, const u16* __restrict__ Wv,
    const float* __restrict__ bq, const float* __restrict__ bk, const float* __restrict__ bv,
    u16* __restrict__ qo, u16* __restrict__ ko, u16* __restrict__ vto) {
    const int K = D_MODEL;
    int z = blockIdx.z;
    const u16* W = (z == 0) ? Wq : (z == 1) ? Wk : Wv;
    const float* bias = (z == 0) ? bq : (z == 1) ? bk : bv;
    int lane = threadIdx.x & 63, wave = threadIdx.x >> 6;
    int l15 = lane & 15, quad = lane >> 4;
    int mw = blockIdx.x * 128 + (wave >> 1) * 64;
    int nw = blockIdx.y * 128 + (wave & 1) * 64;

    f32x4 acc[4][4];
#pragma unroll
    for (int ms = 0; ms < 4; ++ms)
#pragma unroll
        for (int ns = 0; ns < 4; ++ns)
            acc[ms][ns] = (f32x4){0.f, 0.f, 0.f, 0.f};

    gemm_tile_64x64(xb + mw * K, W + nw * K, K, acc, l15, quad);

    const float qscale = 0.125f * 1.4426950408889634f; // attn scale * log2(e)
#pragma unroll
    for (int ns = 0; ns < 4; ++ns) {
        int n = nw + ns * 16 + l15;
        float bv_ = bias[n];
        int h = n >> 6, d = n & 63;
#pragma unroll
        for (int ms = 0; ms < 4; ++ms) {
            int mbase = mw + ms * 16 + quad * 4;
#pragma unroll
            for (int r = 0; r < 4; ++r) {
                int m = mbase + r;
                int b = m >> 11, s = m & (SEQ - 1);
                int bh = b * NH + h;
                float val = acc[ms][ns][r] + bv_;
                if (z == 2) {
                    vto[(bh * DK + d) * SEQ + s] = f2bf(val);
                } else {
                    u16* dst = (z == 0) ? qo : ko;
                    float sc = (z == 0) ? qscale : 1.0f;
                    dst[(bh * SEQ + s) * DK + d] = f2bf(val * sc);
                }
            }
        }
    }
}

// Output projection: fp32 out = A_bf16 @ Wo^T + bo
__global__ __launch_bounds__(256) void out_gemm(
    const u16* __restrict__ ab, const u16* __restrict__ Wo,
    const float* __restrict__ bo, float* __restrict__ out) {
    const int K = D_MODEL;
    int lane = threadIdx.x & 63, wave = threadIdx.x >> 6;
    int l15 = lane & 15, quad = lane >> 4;
    int mw = blockIdx.x * 128 + (wave >> 1) * 64;
    int nw = blockIdx.y * 128 + (wave & 1) * 64;

    f32x4 acc[4][4];
#pragma unroll
    for (int ms = 0; ms < 4; ++ms)
#pragma unroll
        for (int ns = 0; ns < 4; ++ns)
            acc[ms][ns] = (f32x4){0.f, 0.f, 0.f, 0.f};

    gemm_tile_64x64(ab + mw * K, Wo + nw * K, K, acc, l15, quad);

#pragma unroll
    for (int ns = 0; ns < 4; ++ns) {
        int n = nw + ns * 16 + l15;
        float bv_ = bo[n];
#pragma unroll
        for (int ms = 0; ms < 4; ++ms) {
            int mbase = mw + ms * 16 + quad * 4;
#pragma unroll
            for (int r = 0; r < 4; ++r)
                out[(mbase + r) * D_MODEL + n] = acc[ms][ns][r] + bv_;
        }
    }
}

// Causal flash attention. Q pre-scaled by 0.125*log2e -> softmax in exp2 domain.
// Grid: (S/64 q-tiles, B*H). 4 waves/block, 16 q-rows each. K/V read direct from
// global (L1/L2); only P does an LDS round-trip (C-layout -> A-layout).
__global__ __launch_bounds__(256) void attn_kernel(
    const u16* __restrict__ Q, const u16* __restrict__ Kc,
    const u16* __restrict__ Vt, u16* __restrict__ ao) {
    __shared__ __align__(16) u16 Plds[4][16 * 32];
    int qt = blockIdx.x, bh = blockIdx.y;
    int lane = threadIdx.x & 63, wave = threadIdx.x >> 6;
    int l15 = lane & 15, quad = lane >> 4;
    const u16* Qb = Q + bh * (SEQ * DK);
    const u16* Kb = Kc + bh * (SEQ * DK);
    const u16* Vb = Vt + bh * (DK * SEQ);
    int q0 = qt * 64 + wave * 16;

    bf16x8 qf0 = *reinterpret_cast<const bf16x8*>(Qb + (q0 + l15) * DK + quad * 8);
    bf16x8 qf1 = *reinterpret_cast<const bf16x8*>(Qb + (q0 + l15) * DK + quad * 8 + 32);

    float m_i[4], l_i[4];
    f32x4 o[4];
#pragma unroll
    for (int r = 0; r < 4; ++r) { m_i[r] = -__builtin_inff(); l_i[r] = 0.f; }
#pragma unroll
    for (int f = 0; f < 4; ++f) o[f] = (f32x4){0.f, 0.f, 0.f, 0.f};

    int nch = qt * 2 + 2; // chunks of 32 keys, causal bound
    for (int c = 0; c < nch; ++c) {
        int k0 = c * 32;
        f32x4 sfr[2];
#pragma unroll
        for (int n = 0; n < 2; ++n) {
            const u16* kp = Kb + (k0 + n * 16 + l15) * DK + quad * 8;
            f32x4 zacc = (f32x4){0.f, 0.f, 0.f, 0.f};
            zacc = __builtin_amdgcn_mfma_f32_16x16x32_bf16(
                qf0, *reinterpret_cast<const bf16x8*>(kp), zacc, 0, 0, 0);
            zacc = __builtin_amdgcn_mfma_f32_16x16x32_bf16(
                qf1, *reinterpret_cast<const bf16x8*>(kp + 32), zacc, 0, 0, 0);
            int kcol = k0 + n * 16 + l15;
#pragma unroll
            for (int r = 0; r < 4; ++r)
                if (kcol > q0 + quad * 4 + r) zacc[r] = -__builtin_inff();
            sfr[n] = zacc;
        }
        float alpha[4];
#pragma unroll
        for (int r = 0; r < 4; ++r) {
            float v = fmaxf(sfr[0][r], sfr[1][r]);
            v = fmaxf(v, __shfl_xor(v, 1));
            v = fmaxf(v, __shfl_xor(v, 2));
            v = fmaxf(v, __shfl_xor(v, 4));
            v = fmaxf(v, __shfl_xor(v, 8));
            float mn = fmaxf(m_i[r], v); // finite from chunk 0 on (k=0 always valid)
            alpha[r] = exp2f(m_i[r] - mn);
            m_i[r] = mn;
        }
#pragma unroll
        for (int r = 0; r < 4; ++r) {
            float p0 = exp2f(sfr[0][r] - m_i[r]);
            float p1 = exp2f(sfr[1][r] - m_i[r]);
            sfr[0][r] = p0; sfr[1][r] = p1;
            float srow = p0 + p1;
            srow += __shfl_xor(srow, 1);
            srow += __shfl_xor(srow, 2);
            srow += __shfl_xor(srow, 4);
            srow += __shfl_xor(srow, 8);
            l_i[r] = l_i[r] * alpha[r] + srow;
        }
#pragma unroll
        for (int f = 0; f < 4; ++f)
#pragma unroll
            for (int r = 0; r < 4; ++r) o[f][r] *= alpha[r];
        // P: C-layout (row=quad*4+r, col=n*16+l15) -> LDS -> A-layout read
#pragma unroll
        for (int n = 0; n < 2; ++n)
#pragma unroll
            for (int r = 0; r < 4; ++r)
                Plds[wave][(quad * 4 + r) * 32 + n * 16 + l15] = f2bf(sfr[n][r]);
        __asm__ volatile("s_waitcnt lgkmcnt(0)" ::: "memory"); // wave-private LDS RAW
        bf16x8 pf = *reinterpret_cast<const bf16x8*>(&Plds[wave][l15 * 32 + quad * 8]);
#pragma unroll
        for (int f = 0; f < 4; ++f) {
            const u16* vp = Vb + (f * 16 + l15) * SEQ + k0 + quad * 8;
            o[f] = __builtin_amdgcn_mfma_f32_16x16x32_bf16(
                pf, *reinterpret_cast<const bf16x8*>(vp), o[f], 0, 0, 0);
        }
    }
    int b = bh >> 4, h = bh & 15;
#pragma unroll
    for (int f = 0; f < 4; ++f)
#pragma unroll
        for (int r = 0; r < 4; ++r) {
            int q = q0 + quad * 4 + r;
            int d = f * 16 + l15;
            ao[(b * SEQ + q) * D_MODEL + h * DK + d] = f2bf(o[f][r] / l_i[r]);
        }
}

extern "C" void kernel_launch(void* const* d_in, const int* in_sizes, int n_in,
                              void* d_out, int out_size, void* d_ws, size_t ws_size,
                              hipStream_t stream) {
    const float* x  = (const float*)d_in[0];
    const float* Wq = (const float*)d_in[1];
    const float* bq = (const float*)d_in[2];
    const float* Wk = (const float*)d_in[3];
    const float* bk = (const float*)d_in[4];
    const float* Wv = (const float*)d_in[5];
    const float* bv = (const float*)d_in[6];
    const float* Wo = (const float*)d_in[7];
    const float* bo = (const float*)d_in[8];
    float* out = (float*)d_out;
    char* ws = (char*)d_ws;

    // workspace layout (88 MB total)
    const size_t XB   = 16777216; // 8192*1024*2
    const size_t WB   = 2097152;  // 1024*1024*2
    u16* xb  = (u16*)(ws);
    u16* wqb = (u16*)(ws + XB);
    u16* wkb = (u16*)(ws + XB + WB);
    u16* wvb = (u16*)(ws + XB + 2 * WB);
    u16* wob = (u16*)(ws + XB + 3 * WB);
    u16* qb  = (u16*)(ws + XB + 4 * WB);
    u16* kb  = (u16*)(ws + 2 * XB + 4 * WB);
    u16* vtb = (u16*)(ws + 3 * XB + 4 * WB);
    u16* ab  = (u16*)(ws + 4 * XB + 4 * WB);

    cvt_kernel<<<8192, 256, 0, stream>>>(x, xb, 2097152);
    cvt_kernel<<<1024, 256, 0, stream>>>(Wq, wqb, 262144);
    cvt_kernel<<<1024, 256, 0, stream>>>(Wk, wkb, 262144);
    cvt_kernel<<<1024, 256, 0, stream>>>(Wv, wvb, 262144);
    cvt_kernel<<<1024, 256, 0, stream>>>(Wo, wob, 262144);

    qkv_gemm<<<dim3(64, 8, 3), 256, 0, stream>>>(xb, wqb, wkb, wvb, bq, bk, bv,
                                                 qb, kb, vtb);
    attn_kernel<<<dim3(32, 64), 256, 0, stream>>>(qb, kb, vtb, ab);
    out_gemm<<<dim3(64, 8), 256, 0, stream>>>(ab, wob, bo, out);
}

// Round 2
// 600.214 us; speedup vs baseline: 1.3515x; 1.3515x over previous
//
#include <hip/hip_runtime.h>
#include <hip/hip_bf16.h>
#include <stdint.h>

#define D_MODEL 1024
#define SEQ     2048
#define NB      4
#define NH      16
#define DK      64

typedef __bf16 bf16x8 __attribute__((ext_vector_type(8)));
typedef float  f32x4  __attribute__((ext_vector_type(4)));
typedef unsigned short u16;

// fp32 -> bf16 round-to-nearest-even
__device__ __forceinline__ u16 f2bf(float f) {
    uint32_t u = __float_as_uint(f);
    u += 0x7FFFu + ((u >> 16) & 1u);
    return (u16)(u >> 16);
}

__global__ __launch_bounds__(256) void cvt_kernel(const float* __restrict__ src,
                                                  u16* __restrict__ dst, int n4) {
    int i = blockIdx.x * blockDim.x + threadIdx.x;
    if (i >= n4) return;
    float4 v = reinterpret_cast<const float4*>(src)[i];
    ushort4 o;
    o.x = f2bf(v.x); o.y = f2bf(v.y); o.z = f2bf(v.z); o.w = f2bf(v.w);
    reinterpret_cast<ushort4*>(dst)[i] = o;
}

// 64x64 output tile per wave. A: [M,K] K-major bf16 (pointer pre-offset to wave's
// 64 rows), B: [N,K] K-major bf16 (pre-offset). Verified layouts (learn_hip m89/m91):
//   A frag: A[m=lane&15][k=quad*8+j]   B frag: B[k=quad*8+j][n=lane&15]
//   C/D:    col(n)=lane&15, row(m)=quad*4+reg
__device__ __forceinline__ void gemm_tile_64x64(const u16* __restrict__ A,
                                                const u16* __restrict__ B,
                                                int K, f32x4 acc[4][4],
                                                int l15, int quad) {
    const u16* a0 = A + l15 * K + quad * 8;
    const u16* b0 = B + l15 * K + quad * 8;
#pragma unroll 2
    for (int k0 = 0; k0 < K; k0 += 32) {
        bf16x8 af[4], bfr[4];
#pragma unroll
        for (int s = 0; s < 4; ++s) {
            af[s]  = *reinterpret_cast<const bf16x8*>(a0 + s * 16 * K + k0);
            bfr[s] = *reinterpret_cast<const bf16x8*>(b0 + s * 16 * K + k0);
        }
#pragma unroll
        for (int ms = 0; ms < 4; ++ms)
#pragma unroll
            for (int ns = 0; ns < 4; ++ns)
                acc[ms][ns] = __builtin_amdgcn_mfma_f32_16x16x32_bf16(
                    af[ms], bfr[ns], acc[ms][ns], 0, 0, 0);
    }
}

// Fused QKV projection. z=0: Q (scaled by 0.125*log2e) -> [B,H,S,64]
//                       z=1: K -> [B,H,S,64]    z=2: V -> [B,H,64,S] (transposed)
__global__ __launch_bounds__(256) void qkv_gemm(
    const u16* __restrict__ xb,
    const u16* __restrict__ Wq, const u16* __restrict__ Wk, const u16* __restrict__ Wv,
    const float* __restrict__ bq, const float* __restrict__ bk, const float* __restrict__ bv,
    u16* __restrict__ qo, u16* __restrict__ ko, u16* __restrict__ vto) {
    const int K = D_MODEL;
    int z = blockIdx.z;
    const u16* W = (z == 0) ? Wq : (z == 1) ? Wk : Wv;
    const float* bias = (z == 0) ? bq : (z == 1) ? bk : bv;
    int lane = threadIdx.x & 63, wave = threadIdx.x >> 6;
    int l15 = lane & 15, quad = lane >> 4;
    int mw = blockIdx.x * 128 + (wave >> 1) * 64;
    int nw = blockIdx.y * 128 + (wave & 1) * 64;

    f32x4 acc[4][4];
#pragma unroll
    for (int ms = 0; ms < 4; ++ms)
#pragma unroll
        for (int ns = 0; ns < 4; ++ns)
            acc[ms][ns] = (f32x4){0.f, 0.f, 0.f, 0.f};

    gemm_tile_64x64(xb + mw * K, W + nw * K, K, acc, l15, quad);

    const float qscale = 0.125f * 1.4426950408889634f; // attn scale * log2(e)
#pragma unroll
    for (int ns = 0; ns < 4; ++ns) {
        int n = nw + ns * 16 + l15;
        float bv_ = bias[n];
        int h = n >> 6, d = n & 63;
#pragma unroll
        for (int ms = 0; ms < 4; ++ms) {
            int mbase = mw + ms * 16 + quad * 4;
#pragma unroll
            for (int r = 0; r < 4; ++r) {
                int m = mbase + r;
                int b = m >> 11, s = m & (SEQ - 1);
                int bh = b * NH + h;
                float val = acc[ms][ns][r] + bv_;
                if (z == 2) {
                    vto[(bh * DK + d) * SEQ + s] = f2bf(val);
                } else {
                    u16* dst = (z == 0) ? qo : ko;
                    float sc = (z == 0) ? qscale : 1.0f;
                    dst[(bh * SEQ + s) * DK + d] = f2bf(val * sc);
                }
            }
        }
    }
}

// Output projection: fp32 out = A_bf16 @ Wo^T + bo
__global__ __launch_bounds__(256) void out_gemm(
    const u16* __restrict__ ab, const u16* __restrict__ Wo,
    const float* __restrict__ bo, float* __restrict__ out) {
    const int K = D_MODEL;
    int lane = threadIdx.x & 63, wave = threadIdx.x >> 6;
    int l15 = lane & 15, quad = lane >> 4;
    int mw = blockIdx.x * 128 + (wave >> 1) * 64;
    int nw = blockIdx.y * 128 + (wave & 1) * 64;

    f32x4 acc[4][4];
#pragma unroll
    for (int ms = 0; ms < 4; ++ms)
#pragma unroll
        for (int ns = 0; ns < 4; ++ns)
            acc[ms][ns] = (f32x4){0.f, 0.f, 0.f, 0.f};

    gemm_tile_64x64(ab + mw * K, Wo + nw * K, K, acc, l15, quad);

#pragma unroll
    for (int ns = 0; ns < 4; ++ns) {
        int n = nw + ns * 16 + l15;
        float bv_ = bo[n];
#pragma unroll
        for (int ms = 0; ms < 4; ++ms) {
            int mbase = mw + ms * 16 + quad * 4;
#pragma unroll
            for (int r = 0; r < 4; ++r)
                out[(mbase + r) * D_MODEL + n] = acc[ms][ns][r] + bv_;
        }
    }
}

// Causal flash attention, v2.
//  - 64-key chunks (16 QK + 16 PV MFMAs per chunk per wave)
//  - balanced pairing: block handles q-tiles {i, 31-i} -> uniform 33 chunks/wave
//  - P roundtrip LDS stride 72 (16B-aligned reads, <=2-way bank conflict writes)
//  - exp2-domain softmax (Q pre-scaled by 0.125*log2e in qkv_gemm)
// Grid: (16 pairs, B*H). 4 waves/block, 16 q-rows per wave per tile.
#define PSTRIDE 72
__global__ __launch_bounds__(256) void attn_kernel(
    const u16* __restrict__ Q, const u16* __restrict__ Kc,
    const u16* __restrict__ Vt, u16* __restrict__ ao) {
    __shared__ __align__(16) u16 Plds[4][16 * PSTRIDE];
    int pair = blockIdx.x, bh = blockIdx.y;
    int lane = threadIdx.x & 63, wave = threadIdx.x >> 6;
    int l15 = lane & 15, quad = lane >> 4;
    const u16* Qb = Q + bh * (SEQ * DK);
    const u16* Kb = Kc + bh * (SEQ * DK);
    const u16* Vb = Vt + bh * (DK * SEQ);
    int b = bh >> 4, h = bh & 15;
    u16* Pw = &Plds[wave][0];

#pragma unroll 1
    for (int ti = 0; ti < 2; ++ti) {
        int t = ti ? (31 - pair) : pair;
        int q0 = t * 64 + wave * 16;

        bf16x8 qf0 = *reinterpret_cast<const bf16x8*>(Qb + (q0 + l15) * DK + quad * 8);
        bf16x8 qf1 = *reinterpret_cast<const bf16x8*>(Qb + (q0 + l15) * DK + quad * 8 + 32);

        float m_i[4], l_i[4];
        f32x4 o[4];
#pragma unroll
        for (int r = 0; r < 4; ++r) { m_i[r] = -__builtin_inff(); l_i[r] = 0.f; }
#pragma unroll
        for (int f = 0; f < 4; ++f) o[f] = (f32x4){0.f, 0.f, 0.f, 0.f};

        int nch = t + 1; // 64-key chunks up to & including the diagonal chunk
#pragma unroll 1
        for (int c = 0; c < nch; ++c) {
            int k0 = c * 64;
            // ---- QK^T: S[16 q x 64 k] ----
            bf16x8 kf[4][2];
#pragma unroll
            for (int n = 0; n < 4; ++n) {
                const u16* kp = Kb + (k0 + n * 16 + l15) * DK + quad * 8;
                kf[n][0] = *reinterpret_cast<const bf16x8*>(kp);
                kf[n][1] = *reinterpret_cast<const bf16x8*>(kp + 32);
            }
            f32x4 s[4];
#pragma unroll
            for (int n = 0; n < 4; ++n) {
                f32x4 z = (f32x4){0.f, 0.f, 0.f, 0.f};
                z = __builtin_amdgcn_mfma_f32_16x16x32_bf16(qf0, kf[n][0], z, 0, 0, 0);
                z = __builtin_amdgcn_mfma_f32_16x16x32_bf16(qf1, kf[n][1], z, 0, 0, 0);
                s[n] = z;
            }
            if (c == t) { // only the diagonal chunk needs masking
#pragma unroll
                for (int n = 0; n < 4; ++n) {
                    int col = k0 + n * 16 + l15;
#pragma unroll
                    for (int r = 0; r < 4; ++r)
                        if (col > q0 + quad * 4 + r) s[n][r] = -__builtin_inff();
                }
            }
            // ---- online softmax (exp2 domain) ----
            float alpha[4];
#pragma unroll
            for (int r = 0; r < 4; ++r) {
                float v = fmaxf(fmaxf(s[0][r], s[1][r]), fmaxf(s[2][r], s[3][r]));
                v = fmaxf(v, __shfl_xor(v, 1));
                v = fmaxf(v, __shfl_xor(v, 2));
                v = fmaxf(v, __shfl_xor(v, 4));
                v = fmaxf(v, __shfl_xor(v, 8));
                float mn = fmaxf(m_i[r], v);
                alpha[r] = __builtin_amdgcn_exp2f(m_i[r] - mn);
                m_i[r] = mn;
            }
#pragma unroll
            for (int r = 0; r < 4; ++r) {
                float p0 = __builtin_amdgcn_exp2f(s[0][r] - m_i[r]);
                float p1 = __builtin_amdgcn_exp2f(s[1][r] - m_i[r]);
                float p2 = __builtin_amdgcn_exp2f(s[2][r] - m_i[r]);
                float p3 = __builtin_amdgcn_exp2f(s[3][r] - m_i[r]);
                s[0][r] = p0; s[1][r] = p1; s[2][r] = p2; s[3][r] = p3;
                float srow = (p0 + p1) + (p2 + p3);
                srow += __shfl_xor(srow, 1);
                srow += __shfl_xor(srow, 2);
                srow += __shfl_xor(srow, 4);
                srow += __shfl_xor(srow, 8);
                l_i[r] = l_i[r] * alpha[r] + srow;
            }
#pragma unroll
            for (int f = 0; f < 4; ++f)
#pragma unroll
                for (int r = 0; r < 4; ++r) o[f][r] *= alpha[r];
            // ---- P: C-layout -> LDS -> A-layout (wave-private) ----
#pragma unroll
            for (int n = 0; n < 4; ++n)
#pragma unroll
                for (int r = 0; r < 4; ++r)
                    Pw[(quad * 4 + r) * PSTRIDE + n * 16 + l15] = f2bf(s[n][r]);
            __asm__ volatile("s_waitcnt lgkmcnt(0)" ::: "memory");
            bf16x8 pf0 = *reinterpret_cast<const bf16x8*>(Pw + l15 * PSTRIDE + quad * 8);
            bf16x8 pf1 = *reinterpret_cast<const bf16x8*>(Pw + l15 * PSTRIDE + 32 + quad * 8);
            // ---- P @ V: O[16 q x 64 d] ----
#pragma unroll
            for (int f = 0; f < 4; ++f) {
                const u16* vp = Vb + (f * 16 + l15) * SEQ + k0 + quad * 8;
                o[f] = __builtin_amdgcn_mfma_f32_16x16x32_bf16(
                    pf0, *reinterpret_cast<const bf16x8*>(vp), o[f], 0, 0, 0);
                o[f] = __builtin_amdgcn_mfma_f32_16x16x32_bf16(
                    pf1, *reinterpret_cast<const bf16x8*>(vp + 32), o[f], 0, 0, 0);
            }
        }
#pragma unroll
        for (int f = 0; f < 4; ++f)
#pragma unroll
            for (int r = 0; r < 4; ++r) {
                int q = q0 + quad * 4 + r;
                int d = f * 16 + l15;
                ao[(b * SEQ + q) * D_MODEL + h * DK + d] = f2bf(o[f][r] / l_i[r]);
            }
    }
}

extern "C" void kernel_launch(void* const* d_in, const int* in_sizes, int n_in,
                              void* d_out, int out_size, void* d_ws, size_t ws_size,
                              hipStream_t stream) {
    const float* x  = (const float*)d_in[0];
    const float* Wq = (const float*)d_in[1];
    const float* bq = (const float*)d_in[2];
    const float* Wk = (const float*)d_in[3];
    const float* bk = (const float*)d_in[4];
    const float* Wv = (const float*)d_in[5];
    const float* bv = (const float*)d_in[6];
    const float* Wo = (const float*)d_in[7];
    const float* bo = (const float*)d_in[8];
    float* out = (float*)d_out;
    char* ws = (char*)d_ws;

    // workspace layout (88 MB total)
    const size_t XB   = 16777216; // 8192*1024*2
    const size_t WB   = 2097152;  // 1024*1024*2
    u16* xb  = (u16*)(ws);
    u16* wqb = (u16*)(ws + XB);
    u16* wkb = (u16*)(ws + XB + WB);
    u16* wvb = (u16*)(ws + XB + 2 * WB);
    u16* wob = (u16*)(ws + XB + 3 * WB);
    u16* qb  = (u16*)(ws + XB + 4 * WB);
    u16* kb  = (u16*)(ws + 2 * XB + 4 * WB);
    u16* vtb = (u16*)(ws + 3 * XB + 4 * WB);
    u16* ab  = (u16*)(ws + 4 * XB + 4 * WB);

    cvt_kernel<<<8192, 256, 0, stream>>>(x, xb, 2097152);
    cvt_kernel<<<1024, 256, 0, stream>>>(Wq, wqb, 262144);
    cvt_kernel<<<1024, 256, 0, stream>>>(Wk, wkb, 262144);
    cvt_kernel<<<1024, 256, 0, stream>>>(Wv, wvb, 262144);
    cvt_kernel<<<1024, 256, 0, stream>>>(Wo, wob, 262144);

    qkv_gemm<<<dim3(64, 8, 3), 256, 0, stream>>>(xb, wqb, wkb, wvb, bq, bk, bv,
                                                 qb, kb, vtb);
    attn_kernel<<<dim3(16, 64), 256, 0, stream>>>(qb, kb, vtb, ab);
    out_gemm<<<dim3(64, 8), 256, 0, stream>>>(ab, wob, bo, out);
}